// Round 11
// baseline (6959.183 us; speedup 1.0000x reference)
//
#include <hip/hip_runtime.h>
#include <math.h>

#define CDIM 256
#define NHEAD 8
#define HD 32
#define BSZ 8
#define NTOK 256
#define MROWS (BSZ*NTOK)   // 2048
#define LN_EPS 1e-5f
#define DT_STEP 0.01f

// ---- ODE kernel LDS layout (bytes) -----------------------------------------
// red   : f32[8 slabs x 2088], slab=kq, row-stride 258 (padded vs bank aliasing)
// bufA  : f32[8][256] feval arg
// bufB  : f32[8][256] relu(h)
// pS,pQ : f32[8][16]  LN partials [row][wave]
#define RED_SLAB   2088            // f32 per kq slab (8 rows x 258)
#define RED_RSTR   258             // f32 row stride inside slab (even!)
#define OFF_RED    0
#define OFF_BUFA   66816           // 8*2088*4
#define OFF_BUFB   75008
#define OFF_PS     83200
#define OFF_PQ     83712
#define ODE_LDS_BYTES 84224

// ---------------------------------------------------------------------------
// LayerNorm statistics across 256 threads (one column each) for R rows.
// (used by oproj kernel)
// ---------------------------------------------------------------------------
template<int R>
__device__ __forceinline__ void ln_stats(const float* val, int tid,
        float (*part_s)[R], float (*part_q)[R], float* mb, float* rb) {
    const int lane = tid & 63;
    const int wid  = tid >> 6;
    #pragma unroll
    for (int r = 0; r < R; ++r) {
        float s = val[r];
        float q = val[r] * val[r];
        #pragma unroll
        for (int off = 32; off > 0; off >>= 1) {
            s += __shfl_down(s, off, 64);
            q += __shfl_down(q, off, 64);
        }
        if (lane == 0) { part_s[wid][r] = s; part_q[wid][r] = q; }
    }
    __syncthreads();
    if (tid < R) {
        float S = part_s[0][tid] + part_s[1][tid] + part_s[2][tid] + part_s[3][tid];
        float Q = part_q[0][tid] + part_q[1][tid] + part_q[2][tid] + part_q[3][tid];
        float mean = S * (1.0f / CDIM);
        float var  = Q * (1.0f / CDIM) - mean * mean;
        mb[tid] = mean;
        rb[tid] = rsqrtf(var + LN_EPS);
    }
    __syncthreads();
}

// ---------------------------------------------------------------------------
// QKV projection: OUT[M][768] = X[M][256] @ W[256][768] + bias
// ---------------------------------------------------------------------------
__global__ __launch_bounds__(256) void qkv_kernel(
        const float* __restrict__ X, const float* __restrict__ W,
        const float* __restrict__ bias, float* __restrict__ OUT) {
    const int R = 8;
    __shared__ float xs[R][CDIM];
    const int base = blockIdx.x * R;
    const int tid = threadIdx.x;
    #pragma unroll
    for (int r = 0; r < R; ++r) xs[r][tid] = X[(size_t)(base + r) * CDIM + tid];
    __syncthreads();
    for (int g = 0; g < 3; ++g) {
        const int j = g * 256 + tid;
        float acc[R];
        #pragma unroll
        for (int r = 0; r < R; ++r) acc[r] = 0.0f;
        const float* wp = W + j;
        for (int k = 0; k < CDIM; k += 4) {
            float w0 = wp[(size_t)(k+0)*768];
            float w1 = wp[(size_t)(k+1)*768];
            float w2 = wp[(size_t)(k+2)*768];
            float w3 = wp[(size_t)(k+3)*768];
            #pragma unroll
            for (int r = 0; r < R; ++r) {
                float4 xv = *reinterpret_cast<const float4*>(&xs[r][k]);
                acc[r] = fmaf(xv.x, w0, acc[r]);
                acc[r] = fmaf(xv.y, w1, acc[r]);
                acc[r] = fmaf(xv.z, w2, acc[r]);
                acc[r] = fmaf(xv.w, w3, acc[r]);
            }
        }
        const float bb = bias[j];
        #pragma unroll
        for (int r = 0; r < R; ++r) OUT[(size_t)(base + r) * 768 + j] = acc[r] + bb;
    }
}

// ---------------------------------------------------------------------------
// Per-(b,h) attention with online softmax. One WG per (b,h); thread = query row.
// ---------------------------------------------------------------------------
__global__ __launch_bounds__(256) void attn_kernel(
        const float* __restrict__ QKV, float* __restrict__ PO) {
    __shared__ float ks[NTOK][HD];
    __shared__ float vs[NTOK][HD];
    const int bh = blockIdx.x;
    const int b = bh >> 3;
    const int h = bh & 7;
    const int tid = threadIdx.x;
    for (int idx = tid; idx < NTOK * HD; idx += 256) {
        const int j = idx >> 5;
        const int d = idx & 31;
        const float* row = QKV + (size_t)(b * NTOK + j) * 768 + h * HD + d;
        ks[j][d] = row[256];
        vs[j][d] = row[512];
    }
    __syncthreads();
    float q[HD];
    const float* qrow = QKV + (size_t)(b * NTOK + tid) * 768 + h * HD;
    #pragma unroll
    for (int d = 0; d < HD; ++d) q[d] = qrow[d];
    const float scale = 0.17677669529663687f;   // 1/sqrt(32)
    float m = -1e30f, l = 0.0f;
    float po[HD];
    #pragma unroll
    for (int d = 0; d < HD; ++d) po[d] = 0.0f;
    for (int j = 0; j < NTOK; ++j) {
        float s = 0.0f;
        #pragma unroll
        for (int d = 0; d < HD; ++d) s = fmaf(q[d], ks[j][d], s);
        s *= scale;
        const float nm = fmaxf(m, s);
        const float corr = __expf(m - nm);
        const float p = __expf(s - nm);
        l = l * corr + p;
        #pragma unroll
        for (int d = 0; d < HD; ++d) po[d] = fmaf(po[d], corr, p * vs[j][d]);
        m = nm;
    }
    const float inv = 1.0f / l;
    float* dst = PO + (size_t)(b * NTOK + tid) * CDIM + h * HD;
    #pragma unroll
    for (int d = 0; d < HD; ++d) dst[d] = po[d] * inv;
}

// ---------------------------------------------------------------------------
// Out-proj + bias + residual(x) + LayerNorm(g1,b1) -> X1
// ---------------------------------------------------------------------------
__global__ __launch_bounds__(256) void oproj_ln_kernel(
        const float* __restrict__ PO, const float* __restrict__ WO,
        const float* __restrict__ BO, const float* __restrict__ X,
        const float* __restrict__ G1, const float* __restrict__ B1,
        float* __restrict__ X1) {
    const int R = 8;
    __shared__ float ps[R][CDIM];
    __shared__ float part_s[4][R], part_q[4][R];
    __shared__ float mb[R], rb[R];
    const int base = blockIdx.x * R;
    const int tid = threadIdx.x;
    #pragma unroll
    for (int r = 0; r < R; ++r) ps[r][tid] = PO[(size_t)(base + r) * CDIM + tid];
    __syncthreads();
    float acc[R];
    #pragma unroll
    for (int r = 0; r < R; ++r) acc[r] = 0.0f;
    const float* wp = WO + tid;
    for (int k = 0; k < CDIM; k += 4) {
        float w0 = wp[(size_t)(k+0)*CDIM];
        float w1 = wp[(size_t)(k+1)*CDIM];
        float w2 = wp[(size_t)(k+2)*CDIM];
        float w3 = wp[(size_t)(k+3)*CDIM];
        #pragma unroll
        for (int r = 0; r < R; ++r) {
            float4 xv = *reinterpret_cast<const float4*>(&ps[r][k]);
            acc[r] = fmaf(xv.x, w0, acc[r]);
            acc[r] = fmaf(xv.y, w1, acc[r]);
            acc[r] = fmaf(xv.z, w2, acc[r]);
            acc[r] = fmaf(xv.w, w3, acc[r]);
        }
    }
    const float bo = BO[tid];
    float val[R];
    #pragma unroll
    for (int r = 0; r < R; ++r)
        val[r] = acc[r] + bo + X[(size_t)(base + r) * CDIM + tid];
    ln_stats<R>(val, tid, part_s, part_q, mb, rb);
    const float g = G1[tid], bb = B1[tid];
    #pragma unroll
    for (int r = 0; r < R; ++r)
        X1[(size_t)(base + r) * CDIM + tid] = (val[r] - mb[r]) * rb[r] * g + bb;
}

// ---------------------------------------------------------------------------
// bf16 helpers
// ---------------------------------------------------------------------------
__device__ __forceinline__ unsigned int bf16_rne(float x) {
    unsigned int u = __float_as_uint(x);
    return (u + 0x7FFFu + ((u >> 16) & 1u)) >> 16;
}
__device__ __forceinline__ float blo(unsigned int u) { return __uint_as_float(u << 16); }
__device__ __forceinline__ float bhi(unsigned int u) { return __uint_as_float(u & 0xFFFF0000u); }

// ---------------------------------------------------------------------------
// Pack W (f32 [k][c], 256x256) -> WP uint4[8192], indexed (kq*8+cc)*128 + P:
//   k = kq*32 + cc*4 + {0..3},  cols {2P, 2P+1}
//   u.x = w(k0,c0)|w(k1,c0)<<16  u.y = w(k2,c0)|w(k3,c0)<<16
//   u.z = w(k0,c1)|w(k1,c1)<<16  u.w = w(k2,c1)|w(k3,c1)<<16
// ---------------------------------------------------------------------------
__global__ __launch_bounds__(256) void packw_kernel(
        const float* __restrict__ W, uint4* __restrict__ WP) {
    const int idx = blockIdx.x * 256 + threadIdx.x;   // 0..8191
    const int kq = idx >> 10;
    const int cc = (idx >> 7) & 7;
    const int P  = idx & 127;
    const int k0 = kq * 32 + cc * 4;
    const float* p = W + (size_t)k0 * CDIM + 2 * P;
    uint4 u;
    u.x = bf16_rne(p[0*CDIM])   | (bf16_rne(p[1*CDIM])   << 16);
    u.y = bf16_rne(p[2*CDIM])   | (bf16_rne(p[3*CDIM])   << 16);
    u.z = bf16_rne(p[0*CDIM+1]) | (bf16_rne(p[1*CDIM+1]) << 16);
    u.w = bf16_rne(p[2*CDIM+1]) | (bf16_rne(p[3*CDIM+1]) << 16);
    WP[idx] = u;
}

// ---------------------------------------------------------------------------
// k-sliced 2-col GEMV partial. Lane (P,kq): acc[r] (.x=col 2P, .y=col 2P+1)
// over k in [kq*32, kq*32+32). Chunk order rotated by kq so the 8 kq-groups'
// LDS act reads hit disjoint bank groups (conflict-free).
// ---------------------------------------------------------------------------
__device__ __forceinline__ void gemv_part(
        const float* buf /* f32[8][256] */, const uint4* __restrict__ WP,
        int kq, int P, float2* acc) {
    #pragma unroll
    for (int i = 0; i < 8; ++i) {
        const int cc = (i + kq) & 7;
        const uint4 u = WP[(kq * 8 + cc) * 128 + P];
        const float w00 = blo(u.x), w01 = bhi(u.x), w02 = blo(u.y), w03 = bhi(u.y);
        const float w10 = blo(u.z), w11 = bhi(u.z), w12 = blo(u.w), w13 = bhi(u.w);
        const int ka = kq * 32 + cc * 4;
        #pragma unroll
        for (int r = 0; r < 8; ++r) {
            const float4 a = *reinterpret_cast<const float4*>(&buf[r * CDIM + ka]);
            acc[r].x = fmaf(a.w, w03, fmaf(a.z, w02, fmaf(a.y, w01, fmaf(a.x, w00, acc[r].x))));
            acc[r].y = fmaf(a.w, w13, fmaf(a.z, w12, fmaf(a.y, w11, fmaf(a.x, w10, acc[r].y))));
        }
    }
}

// ---------------------------------------------------------------------------
// Persistent ODE kernel — 1024 threads (16 waves, 4/SIMD), 64-VGPR-budget
// design. Lane (w, l): P = w*8 + (l>>3) colpair (cols 2P,2P+1), kq = l&7
// k-slice; owns state for (row kq, cols 2P,2P+1). Weights stream bf16-packed
// from L2 (256KB/CU-feval); acts f32 in LDS; k-reduce via padded red buffer.
// ---------------------------------------------------------------------------
__global__ __launch_bounds__(1024) void ode_kernel(
        const float* __restrict__ X1,
        const uint4* __restrict__ W1P, const float* __restrict__ BL1,
        const uint4* __restrict__ W2P, const float* __restrict__ BL2,
        const float* __restrict__ GN, const float* __restrict__ BN,
        const float* __restrict__ G2, const float* __restrict__ B2,
        const int* __restrict__ LT, const int* __restrict__ NSTEP,
        float* __restrict__ OUT) {
    extern __shared__ char smem[];
    float* red  = reinterpret_cast<float*>(smem + OFF_RED);
    float* bufA = reinterpret_cast<float*>(smem + OFF_BUFA);
    float* bufB = reinterpret_cast<float*>(smem + OFF_BUFB);
    float* pS   = reinterpret_cast<float*>(smem + OFF_PS);   // [8][16]
    float* pQ   = reinterpret_cast<float*>(smem + OFF_PQ);

    const int t  = threadIdx.x;
    const int w  = t >> 6;
    const int l  = t & 63;
    const int pl = l >> 3;
    const int kq = l & 7;
    const int P  = w * 8 + pl;      // 0..127
    const int c0 = 2 * P;

    const int wg = blockIdx.x;
    const int b  = wg >> 5;
    const int rg = wg & 31;
    const int base = b * NTOK + rg * 8;
    int steps = LT[b];
    const int ns = NSTEP[0];
    if (steps > ns) steps = ns;

    const float2 bl1v = *reinterpret_cast<const float2*>(&BL1[c0]);
    const float2 bl2v = *reinterpret_cast<const float2*>(&BL2[c0]);
    const float2 gnv  = *reinterpret_cast<const float2*>(&GN[c0]);
    const float2 bnv  = *reinterpret_cast<const float2*>(&BN[c0]);

    // state: row kq, cols c0,c0+1
    float2 y = *reinterpret_cast<const float2*>(&X1[(size_t)(base + kq) * CDIM + c0]);
    float2 arg = y, kAv, kBv, kCv;

    for (int s = 0; s < steps; ++s) {
        for (int stage = 0; stage < 4; ++stage) {
            // ---- stage arg
            *reinterpret_cast<float2*>(&bufA[kq * CDIM + c0]) = arg;
            __syncthreads();

            // ---- GEMV1 partial
            float2 acc[8];
            #pragma unroll
            for (int r = 0; r < 8; ++r) acc[r] = make_float2(0.0f, 0.0f);
            gemv_part(bufA, W1P, kq, P, acc);
            #pragma unroll
            for (int r = 0; r < 8; ++r)
                *reinterpret_cast<float2*>(&red[kq * RED_SLAB + r * RED_RSTR + c0]) = acc[r];
            __syncthreads();

            // ---- h(row kq, c0..c1) = relu(sum_kq' + bl1)
            float2 h = make_float2(0.0f, 0.0f);
            #pragma unroll
            for (int qq = 0; qq < 8; ++qq) {
                const int q = (qq + kq) & 7;   // rotated read order
                const float2 pr = *reinterpret_cast<const float2*>(
                    &red[q * RED_SLAB + kq * RED_RSTR + c0]);
                h.x += pr.x; h.y += pr.y;
            }
            h.x = fmaxf(h.x + bl1v.x, 0.0f);
            h.y = fmaxf(h.y + bl1v.y, 0.0f);
            *reinterpret_cast<float2*>(&bufB[kq * CDIM + c0]) = h;
            __syncthreads();

            // ---- GEMV2 partial
            #pragma unroll
            for (int r = 0; r < 8; ++r) acc[r] = make_float2(0.0f, 0.0f);
            gemv_part(bufB, W2P, kq, P, acc);
            #pragma unroll
            for (int r = 0; r < 8; ++r)
                *reinterpret_cast<float2*>(&red[kq * RED_SLAB + r * RED_RSTR + c0]) = acc[r];
            __syncthreads();

            // ---- v(row kq) = gemv2 + bl2 + arg; LN over 256 cols of row kq
            float2 v = make_float2(bl2v.x + arg.x, bl2v.y + arg.y);
            #pragma unroll
            for (int qq = 0; qq < 8; ++qq) {
                const int q = (qq + kq) & 7;
                const float2 pr = *reinterpret_cast<const float2*>(
                    &red[q * RED_SLAB + kq * RED_RSTR + c0]);
                v.x += pr.x; v.y += pr.y;
            }
            float S = v.x + v.y;
            float Q = v.x * v.x + v.y * v.y;
            S += __shfl_xor(S, 8, 64);  Q += __shfl_xor(Q, 8, 64);
            S += __shfl_xor(S, 16, 64); Q += __shfl_xor(Q, 16, 64);
            S += __shfl_xor(S, 32, 64); Q += __shfl_xor(Q, 32, 64);
            if (pl == 0) { pS[kq * 16 + w] = S; pQ[kq * 16 + w] = Q; }
            __syncthreads();
            {
                const float4 s0 = *reinterpret_cast<const float4*>(&pS[kq * 16 + 0]);
                const float4 s1 = *reinterpret_cast<const float4*>(&pS[kq * 16 + 4]);
                const float4 s2 = *reinterpret_cast<const float4*>(&pS[kq * 16 + 8]);
                const float4 s3 = *reinterpret_cast<const float4*>(&pS[kq * 16 + 12]);
                const float4 q0 = *reinterpret_cast<const float4*>(&pQ[kq * 16 + 0]);
                const float4 q1 = *reinterpret_cast<const float4*>(&pQ[kq * 16 + 4]);
                const float4 q2 = *reinterpret_cast<const float4*>(&pQ[kq * 16 + 8]);
                const float4 q3 = *reinterpret_cast<const float4*>(&pQ[kq * 16 + 12]);
                S = (s0.x+s0.y+s0.z+s0.w) + (s1.x+s1.y+s1.z+s1.w)
                  + (s2.x+s2.y+s2.z+s2.w) + (s3.x+s3.y+s3.z+s3.w);
                Q = (q0.x+q0.y+q0.z+q0.w) + (q1.x+q1.y+q1.z+q1.w)
                  + (q2.x+q2.y+q2.z+q2.w) + (q3.x+q3.y+q3.z+q3.w);
            }
            const float mean = S * (1.0f / CDIM);
            const float rstd = rsqrtf(Q * (1.0f / CDIM) - mean * mean + LN_EPS);
            float2 kk;
            kk.x = (v.x - mean) * rstd * gnv.x + bnv.x;
            kk.y = (v.y - mean) * rstd * gnv.y + bnv.y;

            // ---- RK4 (3/8 rule) combine
            if (stage == 0) {
                kAv = kk;
                arg.x = fmaf(DT_STEP * (1.0f/3.0f), kk.x, y.x);
                arg.y = fmaf(DT_STEP * (1.0f/3.0f), kk.y, y.y);
            } else if (stage == 1) {
                kBv = kk;
                arg.x = fmaf(DT_STEP, kk.x - kAv.x * (1.0f/3.0f), y.x);
                arg.y = fmaf(DT_STEP, kk.y - kAv.y * (1.0f/3.0f), y.y);
            } else if (stage == 2) {
                kCv = kk;
                arg.x = fmaf(DT_STEP, kAv.x - kBv.x + kk.x, y.x);
                arg.y = fmaf(DT_STEP, kAv.y - kBv.y + kk.y, y.y);
            } else {
                y.x = fmaf(DT_STEP * 0.125f, kAv.x + 3.0f * (kBv.x + kCv.x) + kk.x, y.x);
                y.y = fmaf(DT_STEP * 0.125f, kAv.y + 3.0f * (kBv.y + kCv.y) + kk.y, y.y);
                arg = y;
            }
        }
    }

    // ---- final: OUT = LN(x1 + y, g2, b2)
    const float2 x1v = *reinterpret_cast<const float2*>(&X1[(size_t)(base + kq) * CDIM + c0]);
    float2 v = make_float2(x1v.x + y.x, x1v.y + y.y);
    float S = v.x + v.y;
    float Q = v.x * v.x + v.y * v.y;
    S += __shfl_xor(S, 8, 64);  Q += __shfl_xor(Q, 8, 64);
    S += __shfl_xor(S, 16, 64); Q += __shfl_xor(Q, 16, 64);
    S += __shfl_xor(S, 32, 64); Q += __shfl_xor(Q, 32, 64);
    __syncthreads();   // protect last stage's pS/pQ reads
    if (pl == 0) { pS[kq * 16 + w] = S; pQ[kq * 16 + w] = Q; }
    __syncthreads();
    S = 0.0f; Q = 0.0f;
    #pragma unroll
    for (int wv = 0; wv < 16; ++wv) {
        S += pS[kq * 16 + wv];
        Q += pQ[kq * 16 + wv];
    }
    const float mean = S * (1.0f / CDIM);
    const float rstd = rsqrtf(Q * (1.0f / CDIM) - mean * mean + LN_EPS);
    const float2 g2v = *reinterpret_cast<const float2*>(&G2[c0]);
    const float2 b2v = *reinterpret_cast<const float2*>(&B2[c0]);
    float2 outv;
    outv.x = (v.x - mean) * rstd * g2v.x + b2v.x;
    outv.y = (v.y - mean) * rstd * g2v.y + b2v.y;
    *reinterpret_cast<float2*>(&OUT[(size_t)(base + kq) * CDIM + c0]) = outv;
}

// ---------------------------------------------------------------------------
extern "C" void kernel_launch(void* const* d_in, const int* in_sizes, int n_in,
                              void* d_out, int out_size, void* d_ws, size_t ws_size,
                              hipStream_t stream) {
    const float* x    = (const float*)d_in[0];
    const float* wqkv = (const float*)d_in[1];
    const float* bqkv = (const float*)d_in[2];
    const float* wo   = (const float*)d_in[3];
    const float* bo   = (const float*)d_in[4];
    const float* g1   = (const float*)d_in[5];
    const float* b1   = (const float*)d_in[6];
    const float* g2   = (const float*)d_in[7];
    const float* b2   = (const float*)d_in[8];
    const float* wl1  = (const float*)d_in[9];
    const float* bl1  = (const float*)d_in[10];
    const float* wl2  = (const float*)d_in[11];
    const float* bl2  = (const float*)d_in[12];
    const float* gn   = (const float*)d_in[13];
    const float* bn   = (const float*)d_in[14];
    const int*   lt   = (const int*)d_in[15];
    const int*   nst  = (const int*)d_in[16];

    float* ws  = (float*)d_ws;
    float* qkv = ws;                              // M*768 f32
    float* po  = qkv + (size_t)MROWS * 768;       // M*256 f32
    float* x1  = po  + (size_t)MROWS * CDIM;      // M*256 f32
    uint4* w1p = (uint4*)(x1 + (size_t)MROWS * CDIM);   // 8192 uint4 (128 KB)
    uint4* w2p = w1p + 8192;                            // 8192 uint4 (128 KB)
    float* out = (float*)d_out;

    // Opt in to >64 KiB dynamic LDS (host-side, graph-capture safe, idempotent).
    (void)hipFuncSetAttribute(reinterpret_cast<const void*>(ode_kernel),
                              hipFuncAttributeMaxDynamicSharedMemorySize,
                              ODE_LDS_BYTES);

    hipLaunchKernelGGL(qkv_kernel, dim3(MROWS / 8), dim3(256), 0, stream,
                       x, wqkv, bqkv, qkv);
    hipLaunchKernelGGL(packw_kernel, dim3(32), dim3(256), 0, stream, wl1, w1p);
    hipLaunchKernelGGL(packw_kernel, dim3(32), dim3(256), 0, stream, wl2, w2p);
    hipLaunchKernelGGL(attn_kernel, dim3(BSZ * NHEAD), dim3(256), 0, stream,
                       qkv, po);
    hipLaunchKernelGGL(oproj_ln_kernel, dim3(MROWS / 8), dim3(256), 0, stream,
                       po, wo, bo, x, g1, b1, x1);
    hipLaunchKernelGGL(ode_kernel, dim3(MROWS / 8), dim3(1024), ODE_LDS_BYTES, stream,
                       x1, w1p, bl1, w2p, bl2, gn, bn, g2, b2, lt, nst, out);
}